// Round 9
// baseline (59.640 us; speedup 1.0000x reference)
//
#include <hip/hip_runtime.h>
#include <math.h>

#define BATCH 32
#define ND 512
#define NC 100
#define BIGNEG 1000000.0f
#define PTILE 2048                 // 32i x 64j floats per (block) partial tile
#define NBLK 1024                  // 32b x 4it x 2jt x 4nc

__device__ __forceinline__ int ibase_of(int it) { return (it < 3) ? it * 32 : 68; }

__global__ __launch_bounds__(256, 4) void adv_main(
    const float* __restrict__ z, const float* __restrict__ wu,
    const float* __restrict__ wl, float* __restrict__ P)
{
  // XCD-chunk swizzle (1024 % 8 == 0, bijective); id is b-major -> 4 batches/XCD
  const int flat = blockIdx.x;
  const int id = (flat & 7) * 128 + (flat >> 3);
  const int b  = id >> 5;
  const int r5 = id & 31;
  const int it = r5 >> 3, jt = (r5 >> 2) & 1, nc = r5 & 3;
  const int ib = ibase_of(it);
  const int jb = jt * 40;          // j-tiles {0..63}, {40..103}; 100..103 masked in fin
  const int n0 = nc * 128;

  __shared__ float s_v[128][64];   // rr-scaled wl tile (32 KB)
  __shared__ float s_rr[128];

  const int tid = threadIdx.x;

  // stage rr = width (hi - lo) >= 0
  if (tid < 128) {
    const float* zb = z + (size_t)b * 2 * ND + n0;
    s_rr[tid] = zb[ND + tid] - zb[tid];
  }
  __syncthreads();

  // stage v' = rr * wl tile: 8 float4 per thread, coalesced
  {
    const float* wlb = wl + ((size_t)b * ND + n0) * NC;
#pragma unroll
    for (int k = 0; k < 8; ++k) {
      int fidx = k * 256 + tid;          // 0..2047
      int n = fidx >> 4, c4 = (fidx & 15) << 2;
      int j = jb + c4;
      float4 v = {0.f, 0.f, 0.f, 0.f};
      if (j < NC) v = *(const float4*)(wlb + (size_t)n * NC + j);   // j+3 <= 99 here
      float rr = s_rr[n];
      v.x *= rr; v.y *= rr; v.z *= rr; v.w *= rr;
      *(float4*)&s_v[n][c4] = v;
    }
  }
  __syncthreads();

  // main loop: wave w handles n in [w*32, w*32+32)
  const int w = tid >> 6, l = tid & 63;
  const int io = l >> 3, jo = l & 7;

  float acc[4][8];
#pragma unroll
  for (int k = 0; k < 4; ++k)
#pragma unroll
    for (int m = 0; m < 8; ++m) acc[k][m] = 0.f;

  const float* up   = wu + ((size_t)b * ND + n0 + w * 32) * NC + ib + (io << 2);
  const float* vrow = &s_v[w * 32][jo << 3];
  const float* rrow = &s_rr[w * 32];

#pragma unroll 4
  for (int t = 0; t < 32; ++t) {
    float rr = rrow[t];                                   // ds_read_b32 (broadcast)
    float4 u = *(const float4*)(up + (size_t)t * NC);     // dup gather, L1-resident
    float4 va = *(const float4*)(vrow + t * 64);          // ds_read_b128, 2-way banks
    float4 vb = *(const float4*)(vrow + t * 64 + 4);
    float u0 = rr * u.x, u1 = rr * u.y, u2 = rr * u.z, u3 = rr * u.w;
    float d;
    d = u0 - va.x; acc[0][0] += fabsf(d);  d = u0 - va.y; acc[0][1] += fabsf(d);
    d = u0 - va.z; acc[0][2] += fabsf(d);  d = u0 - va.w; acc[0][3] += fabsf(d);
    d = u0 - vb.x; acc[0][4] += fabsf(d);  d = u0 - vb.y; acc[0][5] += fabsf(d);
    d = u0 - vb.z; acc[0][6] += fabsf(d);  d = u0 - vb.w; acc[0][7] += fabsf(d);
    d = u1 - va.x; acc[1][0] += fabsf(d);  d = u1 - va.y; acc[1][1] += fabsf(d);
    d = u1 - va.z; acc[1][2] += fabsf(d);  d = u1 - va.w; acc[1][3] += fabsf(d);
    d = u1 - vb.x; acc[1][4] += fabsf(d);  d = u1 - vb.y; acc[1][5] += fabsf(d);
    d = u1 - vb.z; acc[1][6] += fabsf(d);  d = u1 - vb.w; acc[1][7] += fabsf(d);
    d = u2 - va.x; acc[2][0] += fabsf(d);  d = u2 - va.y; acc[2][1] += fabsf(d);
    d = u2 - va.z; acc[2][2] += fabsf(d);  d = u2 - va.w; acc[2][3] += fabsf(d);
    d = u2 - vb.x; acc[2][4] += fabsf(d);  d = u2 - vb.y; acc[2][5] += fabsf(d);
    d = u2 - vb.z; acc[2][6] += fabsf(d);  d = u2 - vb.w; acc[2][7] += fabsf(d);
    d = u3 - va.x; acc[3][0] += fabsf(d);  d = u3 - va.y; acc[3][1] += fabsf(d);
    d = u3 - va.z; acc[3][2] += fabsf(d);  d = u3 - va.w; acc[3][3] += fabsf(d);
    d = u3 - vb.x; acc[3][4] += fabsf(d);  d = u3 - vb.y; acc[3][5] += fabsf(d);
    d = u3 - vb.z; acc[3][6] += fabsf(d);  d = u3 - vb.w; acc[3][7] += fabsf(d);
  }

  // cross-wave n-sum via LDS overlay on s_v (stride 33: (33l+k)%32 distinct -> 2-way, free)
  __syncthreads();
  float* s_red = &s_v[0][0];               // need 3*64*33 = 6336 <= 8192 floats
  if (w > 0) {
    float* pr = s_red + (size_t)(w - 1) * 64 * 33 + l * 33;
#pragma unroll
    for (int k = 0; k < 4; ++k)
#pragma unroll
      for (int m = 0; m < 8; ++m) pr[k * 8 + m] = acc[k][m];
  }
  __syncthreads();
  if (w == 0) {
#pragma unroll
    for (int q = 0; q < 3; ++q) {
      const float* pr = s_red + (size_t)q * 64 * 33 + l * 33;
#pragma unroll
      for (int k = 0; k < 4; ++k)
#pragma unroll
        for (int m = 0; m < 8; ++m) acc[k][m] += pr[k * 8 + m];
    }
    float* base = P + (size_t)id * PTILE;  // id = b*32 + it*8 + jt*4 + nc
#pragma unroll
    for (int k = 0; k < 4; ++k) {
      float4 o0 = {acc[k][0], acc[k][1], acc[k][2], acc[k][3]};
      float4 o1 = {acc[k][4], acc[k][5], acc[k][6], acc[k][7]};
      float* rp = base + (((io << 2) + k) << 6) + (jo << 3);
      *(float4*)rp = o0;
      *(float4*)(rp + 4) = o1;
    }
  }
}

__global__ __launch_bounds__(256) void adv_fin(
    const float* __restrict__ z, const float* __restrict__ wu,
    const float* __restrict__ wl, const float* __restrict__ bu,
    const float* __restrict__ bl, const float* __restrict__ y,
    const float* __restrict__ P, float* __restrict__ tmax)
{
  const int b = blockIdx.x >> 2, it = blockIdx.x & 3;
  const int ib = ibase_of(it);
  const int tid = threadIdx.x;

  __shared__ float s_cc[ND];
  __shared__ float s_A[4][32];
  __shared__ float s_B[128];
  __shared__ float s_row[32];
  __shared__ float s_mx[4];

  // cc = lo + hi (2c)
  {
    const float* zb = z + (size_t)b * 2 * ND;
    s_cc[tid]       = zb[tid]       + zb[ND + tid];
    s_cc[tid + 256] = zb[tid + 256] + zb[ND + tid + 256];
  }
  __syncthreads();

  if (tid < 128) {
    // A_i partials: i_local = tid&31, n-quarter = tid>>5
    const int il = tid & 31, nq = tid >> 5;
    const float* p = wu + ((size_t)b * ND + nq * 128) * NC + ib + il;
    float s = 0.f;
#pragma unroll 8
    for (int n = 0; n < 128; ++n) s = fmaf(s_cc[nq * 128 + n], p[(size_t)n * NC], s);
    s_A[nq][il] = s;
  } else {
    // B_j full dot
    const int j = tid - 128;
    const int jc = (j < NC) ? j : NC - 1;
    const float* p = wl + (size_t)b * ND * NC + jc;
    float s = 0.f;
#pragma unroll 8
    for (int n = 0; n < ND; ++n) s = fmaf(s_cc[n], p[(size_t)n * NC], s);
    s_B[j] = s;
  }
  __syncthreads();

  if (tid < 32) {
    const int i = ib + tid;
    s_row[tid] = bu[b * NC + i] - BIGNEG * y[b * NC + i]
               + 0.5f * (s_A[0][tid] + s_A[1][tid] + s_A[2][tid] + s_A[3][tid]);
  }
  __syncthreads();

  // scan: thread -> (jslot = tid&127, i-half = tid>>7)
  const int jslot = tid & 127, ih = tid >> 7;
  const int jt = jslot >> 6, jo = jslot & 63;
  const int j = jt * 40 + jo;
  float m = -INFINITY;
  if (j < NC) {
    const float colt = -bl[b * NC + j] - BIGNEG * (1.0f - y[b * NC + j]) - 0.5f * s_B[j];
    const float* Pb = P + (size_t)(b * 32 + it * 8 + jt * 4) * PTILE + jo;
#pragma unroll 4
    for (int q = 0; q < 16; ++q) {
      const int il = ih * 16 + q;
      float sS = Pb[il * 64] + Pb[PTILE + il * 64]
               + Pb[2 * PTILE + il * 64] + Pb[3 * PTILE + il * 64];
      m = fmaxf(m, 0.5f * sS + s_row[il] + colt);
    }
  }
#pragma unroll
  for (int off = 32; off; off >>= 1) m = fmaxf(m, __shfl_down(m, off, 64));
  if ((tid & 63) == 0) s_mx[tid >> 6] = m;
  __syncthreads();
  if (tid == 0)
    tmax[blockIdx.x] = fmaxf(fmaxf(s_mx[0], s_mx[1]), fmaxf(s_mx[2], s_mx[3]));
}

__global__ void adv_final(const float* __restrict__ tmax, float* __restrict__ out) {
  const int b = threadIdx.x;
  if (b < BATCH) {
    const float* p = tmax + b * 4;
    out[b] = fmaxf(fmaxf(p[0], p[1]), fmaxf(p[2], p[3]));
  }
}

extern "C" void kernel_launch(void* const* d_in, const int* in_sizes, int n_in,
                              void* d_out, int out_size, void* d_ws, size_t ws_size,
                              hipStream_t stream) {
  // inputs: 0:x (unused), 1:z_tensor, 2:w_u, 3:b_u, 4:w_l, 5:b_l, 6:y_tensor
  const float* z  = (const float*)d_in[1];
  const float* wu = (const float*)d_in[2];
  const float* bu = (const float*)d_in[3];
  const float* wl = (const float*)d_in[4];
  const float* bl = (const float*)d_in[5];
  const float* y  = (const float*)d_in[6];
  float* P    = (float*)d_ws;                 // 1024 * 2048 floats = 8.4 MB
  float* tmax = P + (size_t)NBLK * PTILE;     // 128 floats

  adv_main<<<NBLK, 256, 0, stream>>>(z, wu, wl, P);
  adv_fin<<<BATCH * 4, 256, 0, stream>>>(z, wu, wl, bu, bl, y, P, tmax);
  adv_final<<<1, 64, 0, stream>>>(tmax, (float*)d_out);
}

// Round 10
// 39.219 us; speedup vs baseline: 1.5207x; 1.5207x over previous
//
#include <hip/hip_runtime.h>
#include <math.h>

#define BATCH 32
#define ND 512
#define NC 100
#define NSP 16
#define NCHUNK 32              // ND / NSP
#define NDOT 64
#define NTILE 512              // BATCH * NSP
#define PSLOT 10000            // 100*100 floats per (b,ns) partial
#define BIGNEG 1000000.0f

__global__ __launch_bounds__(256, 2) void adv_main(
    const float* __restrict__ z, const float* __restrict__ wu,
    const float* __restrict__ wl, float* __restrict__ P, float* __restrict__ D)
{
  __shared__ float sm[2 * 32 * 128 + 32];   // sU | sV | rr  (32.9 KB)
  const int tid = threadIdx.x;

  if (blockIdx.x < NDOT) {
    // ================= dot blocks: D = sum_n cc_n * w[n][i] =================
    const int id = blockIdx.x;
    const int xcd = id & 7, k = id >> 3;
    const int b = xcd * 4 + (k & 3);
    const int which = k >> 2;               // 0: wu, 1: wl
    const float* w = which ? wl : wu;
    float* cc = sm;                          // [512]
    const float* zb = z + (size_t)b * 2 * ND;
    cc[tid]       = zb[tid]       + zb[ND + tid];
    cc[tid + 256] = zb[tid + 256] + zb[ND + tid + 256];
    __syncthreads();
    const int h = tid >> 7, il = tid & 127;
    float s = 0.f;
    if (il < NC) {
      const float* p = w + ((size_t)b * ND + h * 256) * NC + il;
#pragma unroll 4
      for (int n = 0; n < 256; ++n)
        s = fmaf(cc[h * 256 + n], p[(size_t)n * NC], s);
    }
    __syncthreads();
    float* red = sm;                         // reuse as [256]
    red[tid] = s;
    __syncthreads();
    if (h == 0 && il < NC)
      D[(size_t)(b * 2 + which) * 128 + il] = red[il] + red[128 + il];
    return;
  }

  // ================= tile blocks =================
  const int t0 = blockIdx.x - NDOT;               // 0..511
  const int id = (t0 & 7) * 64 + (t0 >> 3);       // XCD-chunk swizzle (bijective)
  const int b  = id >> 4;
  const int ns = id & 15;
  const int n0 = ns * NCHUNK;

  float* sU = sm;
  float* sV = sm + 32 * 128;
  float* rr = sm + 2 * 32 * 128;

  if (tid < NCHUNK) {
    const float* zb = z + (size_t)b * 2 * ND + n0;
    rr[tid] = zb[ND + tid] - zb[tid];             // width >= 0
  }
  __syncthreads();

  // stage rr-scaled tiles [32][128], cols >= 100 zeroed (never read by fin)
  {
    const float* ub = wu + ((size_t)b * ND + n0) * NC;
    const float* vb = wl + ((size_t)b * ND + n0) * NC;
#pragma unroll
    for (int k = 0; k < 4; ++k) {
      int fidx = k * 256 + tid;                   // 0..1023
      int r = fidx >> 5, c4 = (fidx & 31) << 2;   // c4 in {0,4,...,124}
      float rv = rr[r];
      float4 uu = {0.f, 0.f, 0.f, 0.f}, vv = {0.f, 0.f, 0.f, 0.f};
      if (c4 < NC) {                              // c4 <= 96 -> c4+3 <= 99, no OOB
        uu = *(const float4*)(ub + (size_t)r * NC + c4);
        vv = *(const float4*)(vb + (size_t)r * NC + c4);
      }
      uu.x *= rv; uu.y *= rv; uu.z *= rv; uu.w *= rv;
      vv.x *= rv; vv.y *= rv; vv.z *= rv; vv.w *= rv;
      *(float4*)&sU[r * 128 + c4] = uu;
      *(float4*)&sV[r * 128 + c4] = vv;
    }
  }
  __syncthreads();

  const int w  = tid >> 6, l = tid & 63;
  const int wr = w >> 1, wc = w & 1;
  const int io = l >> 3, jo = l & 7;
  const int ui = wr * 64 + io * 8;
  const int vj = wc * 64 + jo * 8;

  float acc[8][8];
#pragma unroll
  for (int a = 0; a < 8; ++a)
#pragma unroll
    for (int c = 0; c < 8; ++c) acc[a][c] = 0.f;

  const float* pu = sU + ui;
  const float* pv = sV + vj;
#pragma unroll 2
  for (int t = 0; t < NCHUNK; ++t) {
    float4 u0 = *(const float4*)(pu + t * 128);       // 8-way bcast groups, conflict-free
    float4 u1 = *(const float4*)(pu + t * 128 + 4);
    float4 v0 = *(const float4*)(pv + t * 128);
    float4 v1 = *(const float4*)(pv + t * 128 + 4);
    float uu[8] = {u0.x, u0.y, u0.z, u0.w, u1.x, u1.y, u1.z, u1.w};
    float vv[8] = {v0.x, v0.y, v0.z, v0.w, v1.x, v1.y, v1.z, v1.w};
#pragma unroll
    for (int a = 0; a < 8; ++a)
#pragma unroll
      for (int c = 0; c < 8; ++c)
        acc[a][c] += fabsf(uu[a] - vv[c]);            // sub + add(|.|) = 2 VALU/elem
  }

  // masked write of the 100x100 partial tile
  float* pb = P + (size_t)id * PSLOT;
#pragma unroll
  for (int a = 0; a < 8; ++a) {
    const int i = ui + a;
    if (i < NC) {
      float* rowp = pb + (size_t)i * NC;
      if (vj < NC) {
        float4 o = {acc[a][0], acc[a][1], acc[a][2], acc[a][3]};
        *(float4*)(rowp + vj) = o;
      }
      if (vj + 4 < NC) {
        float4 o = {acc[a][4], acc[a][5], acc[a][6], acc[a][7]};
        *(float4*)(rowp + vj + 4) = o;
      }
    }
  }
}

__global__ __launch_bounds__(256) void adv_fin(
    const float* __restrict__ P, const float* __restrict__ D,
    const float* __restrict__ bu, const float* __restrict__ bl,
    const float* __restrict__ y, float* __restrict__ tmax)
{
  const int b = blockIdx.x >> 3, sl = blockIdx.x & 7;
  const int r0 = sl * 13;
  const int nr = (sl == 7) ? 9 : 13;                  // 7*13 + 9 = 100
  const int tid = threadIdx.x;
  __shared__ float s_col[NC];
  __shared__ float s_row[13];
  __shared__ float s_mx[4];

  if (tid < NC)
    s_col[tid] = -0.5f * D[(size_t)(b * 2 + 1) * 128 + tid]
                 - bl[b * NC + tid] - BIGNEG * (1.0f - y[b * NC + tid]);
  if (tid < nr) {
    const int i = r0 + tid;
    s_row[tid] = 0.5f * D[(size_t)(b * 2) * 128 + i]
                 + bu[b * NC + i] - BIGNEG * y[b * NC + i];
  }
  __syncthreads();

  float m = -INFINITY;
  const float* Pb = P + (size_t)(b * 16) * PSLOT + (size_t)r0 * NC;
  const int tot = nr * NC;
  for (int idx = tid; idx < tot; idx += 256) {
    const int r = idx / NC, c = idx - r * NC;
    float s = 0.f;
#pragma unroll
    for (int ns = 0; ns < 16; ++ns) s += Pb[(size_t)ns * PSLOT + idx];
    m = fmaxf(m, 0.5f * s + s_row[r] + s_col[c]);
  }
#pragma unroll
  for (int off = 32; off; off >>= 1) m = fmaxf(m, __shfl_down(m, off, 64));
  if ((tid & 63) == 0) s_mx[tid >> 6] = m;
  __syncthreads();
  if (tid == 0)
    tmax[blockIdx.x] = fmaxf(fmaxf(s_mx[0], s_mx[1]), fmaxf(s_mx[2], s_mx[3]));
}

__global__ void adv_final(const float* __restrict__ tmax, float* __restrict__ out) {
  const int t = threadIdx.x;
  if (t < BATCH) {
    const float* p = tmax + t * 8;
    float m = p[0];
#pragma unroll
    for (int k = 1; k < 8; ++k) m = fmaxf(m, p[k]);
    out[t] = m;
  }
}

extern "C" void kernel_launch(void* const* d_in, const int* in_sizes, int n_in,
                              void* d_out, int out_size, void* d_ws, size_t ws_size,
                              hipStream_t stream) {
  // inputs: 0:x (unused), 1:z_tensor, 2:w_u, 3:b_u, 4:w_l, 5:b_l, 6:y_tensor
  const float* z  = (const float*)d_in[1];
  const float* wu = (const float*)d_in[2];
  const float* bu = (const float*)d_in[3];
  const float* wl = (const float*)d_in[4];
  const float* bl = (const float*)d_in[5];
  const float* y  = (const float*)d_in[6];
  float* P    = (float*)d_ws;                       // 512 * 10000 floats = 20.5 MB
  float* D    = P + (size_t)NTILE * PSLOT;          // 64 * 128 floats
  float* tmax = D + (size_t)NDOT * 128;             // 256 floats

  adv_main<<<NDOT + NTILE, 256, 0, stream>>>(z, wu, wl, P, D);
  adv_fin<<<BATCH * 8, 256, 0, stream>>>(P, D, bu, bl, y, tmax);
  adv_final<<<1, 64, 0, stream>>>(tmax, (float*)d_out);
}

// Round 11
// 12.187 us; speedup vs baseline: 4.8936x; 3.2180x over previous
//
#include <hip/hip_runtime.h>
#include <math.h>
#include <stdint.h>

#define BATCH 32
#define ND 512
#define NC 100
#define BIGNEG 1000000.0f

__device__ __forceinline__ float rdlane_f(float v, int t) {
  return __uint_as_float(__builtin_amdgcn_readlane(__float_as_uint(v), (uint32_t)t));
}

// One block per batch. Key fact: y is one-hot, so b_f's -BIG masks kill every
// (i,j) except j = j* (the label) with i != j*; the global max is therefore
// max_i upper[b, i, j*]. Work drops 100x vs the full (i,j) tensor.
__global__ __launch_bounds__(1024, 2) void adv_one(
    const float* __restrict__ z, const float* __restrict__ wu,
    const float* __restrict__ bu, const float* __restrict__ wl,
    const float* __restrict__ bl, const float* __restrict__ y,
    float* __restrict__ out)
{
  const int b   = blockIdx.x;
  const int tid = threadIdx.x;
  const int wv  = tid >> 6, l = tid & 63;
  const int pair = wv >> 1, half = wv & 1;   // 8 pairs x 64 n; 2 waves/pair cover i 0..127

  __shared__ int   s_js;
  __shared__ float s_dq[8];
  __shared__ float s_amp[8][128];
  __shared__ float s_dot[8][128];
  __shared__ float s_mx[16];

  if (tid == 0) s_js = 0;
  __syncthreads();
  if (tid < NC && y[b * NC + tid] > 0.5f) s_js = tid;   // one-hot -> single writer
  __syncthreads();
  const int js = s_js;

  // lane l of each wave owns n = pair*64 + l
  const int n = (pair << 6) + l;
  const float* zb = z + (size_t)b * 2 * ND;
  const float zlo = zb[n], zhi = zb[ND + n];
  const float cc = zlo + zhi;          // 2*center
  const float rr = zhi - zlo;          // 2*radius >= 0
  const float qv = wl[((size_t)b * ND + n) * NC + js];

  // dotQ = sum_n cc_n * q_n  (per-pair partial, computed once by half==0 wave)
  if (half == 0) {
    float p = cc * qv;
#pragma unroll
    for (int off = 1; off < 64; off <<= 1) p += __shfl_xor(p, off, 64);
    if (l == 0) s_dq[pair] = p;
  }

  const int i  = (half << 6) + l;
  const int iL = (i < NC) ? i : NC - 1;          // clamp (dup of i=99, masked later)
  const float* up = wu + ((size_t)b * ND + (pair << 6)) * NC + iL;

  float amp = 0.f, dotu = 0.f;
#pragma unroll 8
  for (int t = 0; t < 64; ++t) {
    float u  = up[(size_t)t * NC];               // coalesced, L2-resident
    float cs = rdlane_f(cc, t);
    float rs = rdlane_f(rr, t);
    float qs = rdlane_f(qv, t);
    float d  = u - qs;
    amp  = fmaf(rs, fabsf(d), amp);
    dotu = fmaf(cs, u, dotu);
  }
  s_amp[pair][tid & 127] = amp;
  s_dot[pair][tid & 127] = dotu;
  __syncthreads();

  float m = -INFINITY;
  if (tid < NC) {
    float A = 0.f, Du = 0.f, dq = 0.f;
#pragma unroll
    for (int p = 0; p < 8; ++p) {
      A += s_amp[p][tid]; Du += s_dot[p][tid]; dq += s_dq[p];
    }
    // upper[b, i, j*] = bu_i - bl_j* - BIG*y_i + 0.5*(Du - dq + A)
    m = bu[b * NC + tid] - BIGNEG * y[b * NC + tid] - bl[b * NC + js]
        + 0.5f * (Du - dq + A);
  }
#pragma unroll
  for (int off = 32; off; off >>= 1) m = fmaxf(m, __shfl_down(m, off, 64));
  if (l == 0) s_mx[wv] = m;
  __syncthreads();
  if (tid == 0) {
    float r = s_mx[0];
#pragma unroll
    for (int k = 1; k < 16; ++k) r = fmaxf(r, s_mx[k]);
    out[b] = r;
  }
}

extern "C" void kernel_launch(void* const* d_in, const int* in_sizes, int n_in,
                              void* d_out, int out_size, void* d_ws, size_t ws_size,
                              hipStream_t stream) {
  // inputs: 0:x (unused), 1:z_tensor, 2:w_u, 3:b_u, 4:w_l, 5:b_l, 6:y_tensor
  const float* z  = (const float*)d_in[1];
  const float* wu = (const float*)d_in[2];
  const float* bu = (const float*)d_in[3];
  const float* wl = (const float*)d_in[4];
  const float* bl = (const float*)d_in[5];
  const float* y  = (const float*)d_in[6];

  adv_one<<<BATCH, 1024, 0, stream>>>(z, wu, bu, wl, bl, y, (float*)d_out);
}

// Round 12
// 11.755 us; speedup vs baseline: 5.0738x; 1.0368x over previous
//
#include <hip/hip_runtime.h>
#include <math.h>
#include <stdint.h>

#define BATCH 32
#define ND 512
#define NC 100
#define NQ 8            // n-chunks of 64
#define BIGNEG 1000000.0f

__device__ __forceinline__ float rdlane_f(float v, int t) {
  return __uint_as_float(__builtin_amdgcn_readlane(__float_as_uint(v), (uint32_t)t));
}

// y is one-hot: b_f's -BIG masks kill all (i,j) except j = j* (label), i != j*.
// out[b] = max_i  bu_i - BIG*y_i - bl_j* + 0.5*(Du_i - dq + A_i)
//   Du_i = sum_n cc_n*wu[n][i],  dq = sum_n cc_n*wl[n][j*],
//   A_i  = sum_n rr_n*|wu[n][i]-wl[n][j*]|,  cc = lo+hi, rr = hi-lo.
// Partial kernel: 256 blocks = 32 b x 8 nq (64 n each) -> 1 block/CU.
__global__ __launch_bounds__(128, 8) void adv_part(
    const float* __restrict__ z, const float* __restrict__ wu,
    const float* __restrict__ wl, const float* __restrict__ y,
    float* __restrict__ P)
{
  // XCD-chunk swizzle (256 = 8*32, bijective), b-major -> 4 batches per XCD
  const int id = ((blockIdx.x & 7) << 5) + (blockIdx.x >> 3);
  const int b = id >> 3, nq = id & 7;
  const int tid  = threadIdx.x;
  const int half = tid >> 6, l = tid & 63;

  __shared__ int   s_js;
  __shared__ float s_dq;

  if (tid == 0) s_js = 0;
  __syncthreads();
  if (tid < NC && y[b * NC + tid] > 0.5f) s_js = tid;
  __syncthreads();
  const int js = s_js;

  // lane l holds n = nq*64 + l's cc/rr/q (both waves load the same values)
  const int n0 = nq << 6;
  const int n  = n0 + l;
  const float* zb = z + (size_t)b * 2 * ND;
  const float zlo = zb[n], zhi = zb[ND + n];
  const float cc = zlo + zhi;
  const float rr = zhi - zlo;           // >= 0
  const float qv = wl[((size_t)b * ND + n) * NC + js];

  if (half == 0) {                       // dq partial for this n-chunk
    float p = cc * qv;
#pragma unroll
    for (int off = 1; off < 64; off <<= 1) p += __shfl_xor(p, off, 64);
    if (l == 0) s_dq = p;
  }

  const int i  = (half << 6) + l;
  const int iL = (i < NC) ? i : NC - 1;
  const float* up = wu + ((size_t)b * ND + n0) * NC + iL;

  float amp = 0.f, dotu = 0.f;
#pragma unroll 16
  for (int t = 0; t < 64; ++t) {
    float u  = up[(size_t)t * NC];      // coalesced, L2/HBM pipelined
    float cs = rdlane_f(cc, t);
    float rs = rdlane_f(rr, t);
    float qs = rdlane_f(qv, t);
    float d  = u - qs;
    amp  = fmaf(rs, fabsf(d), amp);
    dotu = fmaf(cs, u, dotu);
  }
  __syncthreads();
  P[(size_t)id * 128 + tid] = amp + dotu - s_dq;
}

__global__ __launch_bounds__(128) void adv_fin(
    const float* __restrict__ P, const float* __restrict__ bu,
    const float* __restrict__ bl, const float* __restrict__ y,
    float* __restrict__ out)
{
  const int b = blockIdx.x, tid = threadIdx.x;
  __shared__ int   s_js;
  __shared__ float s_mx[2];

  if (tid == 0) s_js = 0;
  __syncthreads();
  if (tid < NC && y[b * NC + tid] > 0.5f) s_js = tid;
  __syncthreads();
  const int js = s_js;

  float m = -INFINITY;
  if (tid < NC) {
    const float* pb = P + ((size_t)b * NQ) * 128 + tid;
    float s = 0.f;
#pragma unroll
    for (int q = 0; q < NQ; ++q) s += pb[q * 128];   // coalesced, L2-resident
    m = bu[b * NC + tid] - BIGNEG * y[b * NC + tid] - bl[b * NC + js] + 0.5f * s;
  }
#pragma unroll
  for (int off = 32; off; off >>= 1) m = fmaxf(m, __shfl_down(m, off, 64));
  if ((tid & 63) == 0) s_mx[tid >> 6] = m;
  __syncthreads();
  if (tid == 0) out[b] = fmaxf(s_mx[0], s_mx[1]);
}

extern "C" void kernel_launch(void* const* d_in, const int* in_sizes, int n_in,
                              void* d_out, int out_size, void* d_ws, size_t ws_size,
                              hipStream_t stream) {
  // inputs: 0:x (unused), 1:z_tensor, 2:w_u, 3:b_u, 4:w_l, 5:b_l, 6:y_tensor
  const float* z  = (const float*)d_in[1];
  const float* wu = (const float*)d_in[2];
  const float* bu = (const float*)d_in[3];
  const float* wl = (const float*)d_in[4];
  const float* bl = (const float*)d_in[5];
  const float* y  = (const float*)d_in[6];
  float* P = (float*)d_ws;    // 256 * 128 floats = 128 KB

  adv_part<<<BATCH * NQ, 128, 0, stream>>>(z, wu, wl, y, P);
  adv_fin<<<BATCH, 128, 0, stream>>>(P, bu, bl, y, (float*)d_out);
}